// Round 15
// baseline (899.437 us; speedup 1.0000x reference)
//
#include <hip/hip_runtime.h>
#include <hip/hip_bf16.h>

#define BATCHN 512
#define SEQL 28
#define DIMM 512
#define DINNER 1024
#define DSTATE 16
#define DTRANK 32
#define XDBW 64                 // DT_RANK + 2*D_STATE
#define EPSV 1e-6f
#define LDK 40                  // padded LDS stride for scan's lA only
#define LOG2E 1.442695041f
#define LN2F 0.6931471806f

typedef __hip_bfloat16 bf16;
using f32x4 = __attribute__((ext_vector_type(4))) float;
using bf16x8 = __attribute__((ext_vector_type(8))) short;

typedef __attribute__((address_space(1))) const void* gas1_t;
typedef __attribute__((address_space(3))) void* las3_t;

__device__ __forceinline__ float lo16(unsigned u) {
    unsigned short h = (unsigned short)u; bf16 v = *(bf16*)&h; return __bfloat162float(v);
}
__device__ __forceinline__ float hi16(unsigned u) {
    unsigned short h = (unsigned short)(u >> 16); bf16 v = *(bf16*)&h; return __bfloat162float(v);
}
__device__ __forceinline__ float softplus_fast(float v) {
    return (v > 20.f) ? v : LN2F * __log2f(1.f + exp2f(v * LOG2E));
}

// ---------------- weight f32 -> bf16 conversion (once per launch) ----------------
__global__ __launch_bounds__(256) void wcvt_kernel(const float* __restrict__ s,
                                                   bf16* __restrict__ d, int n) {
    int i = (blockIdx.x * 256 + threadIdx.x) * 8;
    if (i < n) {
        float4 a = *(const float4*)(s + i), b = *(const float4*)(s + i + 4);
        bf16 t[8];
        t[0] = __float2bfloat16(a.x); t[1] = __float2bfloat16(a.y);
        t[2] = __float2bfloat16(a.z); t[3] = __float2bfloat16(a.w);
        t[4] = __float2bfloat16(b.x); t[5] = __float2bfloat16(b.y);
        t[6] = __float2bfloat16(b.z); t[7] = __float2bfloat16(b.w);
        *(uint4*)(d + i) = *(uint4*)t;
    }
}

// ---------------- row projection: h[r,d] = W[d,:28] . x[r,:28] + b[d] ----------------
__global__ __launch_bounds__(256) void rp_kernel(const float* __restrict__ x,
                                                 const float* __restrict__ w,
                                                 const float* __restrict__ b,
                                                 float* __restrict__ h) {
    int row = blockIdx.x;
    int d = blockIdx.y * blockDim.x + threadIdx.x;
    __shared__ float xin[28];
    if (threadIdx.x < 28) xin[threadIdx.x] = x[row * 28 + threadIdx.x];
    __syncthreads();
    float acc = b[d];
#pragma unroll
    for (int k = 0; k < 28; ++k) acc = fmaf(w[d * 28 + k], xin[k], acc);
    h[(size_t)row * DIMM + d] = acc;
}

// ---------------- RMSNorm -> bf16 nh buffer (wave per row) ----------------
__global__ __launch_bounds__(256) void rmsn_kernel(const float* __restrict__ h,
                                                   const float* __restrict__ nw,
                                                   bf16* __restrict__ nh) {
    int row = blockIdx.x * blockDim.y + threadIdx.y;
    int lane = threadIdx.x;
    const float4* p = (const float4*)(h + (size_t)row * DIMM);
    float4 v0 = p[lane * 2], v1 = p[lane * 2 + 1];
    float ss = v0.x * v0.x + v0.y * v0.y + v0.z * v0.z + v0.w * v0.w +
               v1.x * v1.x + v1.y * v1.y + v1.z * v1.z + v1.w * v1.w;
#pragma unroll
    for (int off = 32; off > 0; off >>= 1) ss += __shfl_down(ss, off);
    ss = __shfl(ss, 0);
    float inv = rsqrtf(ss * (1.f / DIMM) + EPSV);
    const float4* wp = (const float4*)nw;
    float4 w0 = wp[lane * 2], w1 = wp[lane * 2 + 1];
    bf16 tmp[8];
    tmp[0] = __float2bfloat16(v0.x * inv * w0.x);
    tmp[1] = __float2bfloat16(v0.y * inv * w0.y);
    tmp[2] = __float2bfloat16(v0.z * inv * w0.z);
    tmp[3] = __float2bfloat16(v0.w * inv * w0.w);
    tmp[4] = __float2bfloat16(v1.x * inv * w1.x);
    tmp[5] = __float2bfloat16(v1.y * inv * w1.y);
    tmp[6] = __float2bfloat16(v1.z * inv * w1.z);
    tmp[7] = __float2bfloat16(v1.w * inv * w1.w);
    *(uint4*)(nh + (size_t)row * DIMM + lane * 8) = *(uint4*)tmp;
}

// ---------------- MFMA GEMM core (r13, unchanged): global_load_lds staging ----------------
template <typename TC, int BM, int BN, bool ADDC, bool HASBIAS, int SPLITK, bool COAL>
__device__ __forceinline__ void gemm_core(char* smem,
                                          const bf16* __restrict__ A, int lda,
                                          const bf16* __restrict__ W,
                                          const float* __restrict__ bias,
                                          TC* __restrict__ C, int ldc,
                                          int Kfull, size_t c_split, int bz) {
    constexpr int BK = 32;
    constexpr int MI = (BN == 128) ? 4 : 1;
    constexpr int NI = 4;
    bf16* As = (bf16*)smem;
    bf16* Bs = As + BM * BK;
    const int t = threadIdx.x;
    const int w = t >> 6, l = t & 63;
    const int bm = blockIdx.x * BM;
    const int bn = blockIdx.y * BN;
    const int wm = (BN == 128) ? (w >> 1) * 64 : w * 16;
    const int wn = (BN == 128) ? (w & 1) * 64 : 0;
    const int Kloop = Kfull / SPLITK;
    const int kb = (SPLITK > 1) ? bz * Kloop : 0;
    if (SPLITK > 1) C += (size_t)bz * c_split;

    f32x4 acc[MI][NI] = {};
    constexpr int CHA = BM / 64;
    constexpr int CHB = BN / 64;
    const int lrow = l >> 2;
    const int lcol = (l & 3) * 8;

    for (int k0 = 0; k0 < Kloop; k0 += BK) {
        const int kcur = kb + k0;
        __syncthreads();
#pragma unroll
        for (int i = 0; i < CHA; ++i) {
            int chunk = w * CHA + i;
            int row = chunk * 16 + lrow;
            __builtin_amdgcn_global_load_lds(
                (gas1_t)(const void*)(A + (size_t)(bm + row) * lda + kcur + lcol),
                (las3_t)(void*)(As + chunk * 512), 16, 0, 0);
        }
#pragma unroll
        for (int i = 0; i < CHB; ++i) {
            int chunk = w * CHB + i;
            int row = chunk * 16 + lrow;
            __builtin_amdgcn_global_load_lds(
                (gas1_t)(const void*)(W + (size_t)(bn + row) * Kfull + kcur + lcol),
                (las3_t)(void*)(Bs + chunk * 512), 16, 0, 0);
        }
        __syncthreads();
        bf16x8 af[MI], bfr[NI];
#pragma unroll
        for (int mi = 0; mi < MI; ++mi)
            af[mi] = *(const bf16x8*)(&As[(wm + mi * 16 + (l & 15)) * BK + (l >> 4) * 8]);
#pragma unroll
        for (int ni = 0; ni < NI; ++ni)
            bfr[ni] = *(const bf16x8*)(&Bs[(wn + ni * 16 + (l & 15)) * BK + (l >> 4) * 8]);
#pragma unroll
        for (int mi = 0; mi < MI; ++mi)
#pragma unroll
            for (int ni = 0; ni < NI; ++ni)
                acc[mi][ni] = __builtin_amdgcn_mfma_f32_16x16x32_bf16(af[mi], bfr[ni], acc[mi][ni], 0, 0, 0);
    }

    if constexpr (COAL && sizeof(TC) == 2) {
        __syncthreads();
        bf16* my = (bf16*)smem + w * (16 * 72);
        float bv[NI];
#pragma unroll
        for (int ni = 0; ni < NI; ++ni)
            bv[ni] = HASBIAS ? bias[bn + wn + ni * 16 + (l & 15)] : 0.f;
#pragma unroll
        for (int mi = 0; mi < MI; ++mi) {
#pragma unroll
            for (int ni = 0; ni < NI; ++ni)
#pragma unroll
                for (int r = 0; r < 4; ++r)
                    my[(((l >> 4) << 2) + r) * 72 + ni * 16 + (l & 15)] =
                        __float2bfloat16(acc[mi][ni][r] + bv[ni]);
            __syncthreads();
#pragma unroll
            for (int p = 0; p < 2; ++p) {
                int idx = p * 64 + l;
                int rr = idx >> 3, c8 = (idx & 7) * 8;
                uint4 vv = *(const uint4*)(&my[rr * 72 + c8]);
                *(uint4*)((bf16*)C + (size_t)(bm + wm + mi * 16 + rr) * ldc + bn + wn + c8) = vv;
            }
            __syncthreads();
        }
    } else if constexpr (COAL && sizeof(TC) == 4) {
        __syncthreads();
        float* myf = (float*)smem + w * (16 * 72);
        float bv[NI];
#pragma unroll
        for (int ni = 0; ni < NI; ++ni)
            bv[ni] = HASBIAS ? bias[bn + wn + ni * 16 + (l & 15)] : 0.f;
#pragma unroll
        for (int mi = 0; mi < MI; ++mi) {
#pragma unroll
            for (int ni = 0; ni < NI; ++ni)
#pragma unroll
                for (int r = 0; r < 4; ++r)
                    myf[(((l >> 4) << 2) + r) * 72 + ni * 16 + (l & 15)] = acc[mi][ni][r] + bv[ni];
            __syncthreads();
            int rr = l >> 2, c0 = l & 3;
            float* crow = (float*)C + (size_t)(bm + wm + mi * 16 + rr) * ldc + bn + wn;
#pragma unroll
            for (int c = 0; c < 4; ++c) {
                int slot = c0 + 4 * c;
                float4 v = *(float4*)(&myf[rr * 72 + slot * 4]);
                if (ADDC) {
                    float4 cc = *(const float4*)(crow + slot * 4);
                    v.x += cc.x; v.y += cc.y; v.z += cc.z; v.w += cc.w;
                }
                *(float4*)(crow + slot * 4) = v;
            }
            __syncthreads();
        }
    } else {
#pragma unroll
        for (int mi = 0; mi < MI; ++mi)
#pragma unroll
            for (int ni = 0; ni < NI; ++ni) {
                int col = bn + wn + ni * 16 + (l & 15);
                int rowb = bm + wm + mi * 16 + ((l >> 4) << 2);
                float bv = HASBIAS ? bias[col] : 0.f;
#pragma unroll
                for (int r = 0; r < 4; ++r) {
                    float v = acc[mi][ni][r] + bv;
                    size_t off = (size_t)(rowb + r) * ldc + col;
                    if (ADDC) v += ((float*)C)[off];
                    ((float*)C)[off] = v;
                }
            }
    }
}

__global__ __launch_bounds__(256) void g_inproj(const bf16* A, const bf16* W, const float* bias,
                                                bf16* C) {
    __shared__ char smem[16384];
    gemm_core<bf16, 128, 128, false, true, 1, true>(smem, A, DIMM, W, bias, C, 2 * DINNER, DIMM, 0, 0);
}
__global__ __launch_bounds__(256) void g_xdbk(const bf16* A, const bf16* W, float* C, size_t c_split) {
    __shared__ char smem[8192];
    gemm_core<float, 64, 64, false, false, 2, false>(smem, A, 2 * DINNER, W, nullptr, C, XDBW, DINNER,
                                                     c_split, blockIdx.z);
}
__global__ __launch_bounds__(256) void g_outproj(const bf16* A, const bf16* W, const float* bias,
                                                 float* C) {
    __shared__ char smem[18432];
    gemm_core<float, 128, 128, true, true, 1, true>(smem, A, 2 * DINNER, W, bias, C, DIMM, DINNER, 0, 0);
}

// ---------------- depthwise causal conv (k=4) + SiLU; in-place on x-half; 2 d/thread ----------------
__global__ __launch_bounds__(256) void conv_kernel(bf16* __restrict__ xz,
                                                   const float* __restrict__ cw,
                                                   const float* __restrict__ cb) {
    int gid = blockIdx.x * blockDim.x + threadIdx.x;
    int b = gid >> 9, dp = gid & 511;
    int d = dp * 2;
    float4 wA = *(const float4*)(cw + d * 4);
    float4 wB = *(const float4*)(cw + d * 4 + 4);
    float bA = cb[d], bB = cb[d + 1];
    bf16* col = xz + (size_t)b * SEQL * (2 * DINNER) + d;
    float a0 = 0.f, a1 = 0.f, a2 = 0.f, b0 = 0.f, b1 = 0.f, b2 = 0.f;
#pragma unroll
    for (int t = 0; t < SEQL; ++t) {
        unsigned u = *(const unsigned*)(col + (size_t)t * (2 * DINNER));
        float a3 = lo16(u), b3 = hi16(u);
        float va = fmaf(wA.x, a0, fmaf(wA.y, a1, fmaf(wA.z, a2, fmaf(wA.w, a3, bA))));
        float vb = fmaf(wB.x, b0, fmaf(wB.y, b1, fmaf(wB.z, b2, fmaf(wB.w, b3, bB))));
        float sa = va * __builtin_amdgcn_rcpf(1.f + exp2f(-va * LOG2E));
        float sb = vb * __builtin_amdgcn_rcpf(1.f + exp2f(-vb * LOG2E));
        bf16 ra = __float2bfloat16(sa), rb = __float2bfloat16(sb);
        unsigned ur = ((unsigned)*(unsigned short*)&rb << 16) | *(unsigned short*)&ra;
        *(unsigned*)(col + (size_t)t * (2 * DINNER)) = ur;
        a0 = a1; a1 = a2; a2 = a3;
        b0 = b1; b1 = b2; b2 = b3;
    }
}

// ---------------- fused scan v3: register-prefetched sequence ----------------
// r14 showed VALUBusy 36% / occ 29%: the serial t-loop stalls on per-t global x/z
// reads. Their addresses are loop-invariant -> prefetch ALL 28 t into register
// arrays at kernel top (latency hides under the dt-MFMA phase), fully unroll the
// t-loop (static indexing, rule #20). launch_bounds(128,1): LDS (7 blocks/CU) is
// the binding occupancy limit, so the +60 VGPR is free.
__global__ __launch_bounds__(128, 1) void scan_kernel(bf16* __restrict__ xz,
                                                      const float* __restrict__ xdb0,
                                                      const float* __restrict__ xdb1,
                                                      const float* __restrict__ dtw,
                                                      const float* __restrict__ dtb,
                                                      const float* __restrict__ A_log,
                                                      const float* __restrict__ Dp) {
    const int b = blockIdx.x >> 2;
    const int d0 = (blockIdx.x & 3) << 8;
    const int tid = threadIdx.x;            // 0..127
    const int w = tid >> 6, l = tid & 63;   // 2 waves

    __shared__ bf16 ldt[SEQL][264];
    __shared__ bf16 lA[32][LDK];
    __shared__ float lBC[SEQL][36];

    const int dc = d0 + 2 * tid;
    bf16* xg = xz + (size_t)b * SEQL * (2 * DINNER) + dc;

    // ---- prefetch the full sequence into registers (issued first; latency
    //      hides under staging + dt-MFMA below) ----
    unsigned xu[SEQL], zu[SEQL];
#pragma unroll
    for (int t = 0; t < SEQL; ++t) {
        xu[t] = *(const unsigned*)(xg + (size_t)t * (2 * DINNER));
        zu[t] = *(const unsigned*)(xg + (size_t)t * (2 * DINNER) + DINNER);
    }

    const float* xr0 = xdb0 + (size_t)b * SEQL * XDBW;
    const float* xr1 = xdb1 + (size_t)b * SEQL * XDBW;

    // ---- stage A = xdb_dt (28x32, summed halves, f32->bf16, rows 28-31 zero) ----
#pragma unroll
    for (int k = 0; k < 8; ++k) {
        int flat = k * 128 + tid;
        int t = flat >> 5, j = flat & 31;
        float v = (t < SEQL) ? xr0[t * XDBW + j] + xr1[t * XDBW + j] : 0.f;
        lA[t][j] = __float2bfloat16(v);
    }
    // ---- stage B/C (28x32, summed) ----
#pragma unroll
    for (int k = 0; k < 7; ++k) {
        int idx = k * 128 + tid;
        int t = idx >> 5, j = idx & 31;
        lBC[t][j] = xr0[t * XDBW + 32 + j] + xr1[t * XDBW + 32 + j];
    }
    __syncthreads();

    // ---- dt = softplus(xdb_dt @ dtw^T + dtb) via MFMA; wave w covers cols w*128..+127 ----
    {
        const int col = l & 15;
        const int ksl = (l >> 4) * 8;
        bf16x8 a0 = *(const bf16x8*)(&lA[col][ksl]);
        bf16x8 a1 = *(const bf16x8*)(&lA[16 + col][ksl]);
#pragma unroll
        for (int ni = 0; ni < 8; ++ni) {
            int dl = w * 128 + ni * 16 + col;
            const float* br = dtw + (size_t)(d0 + dl) * DTRANK + ksl;
            bf16x8 bv;
#pragma unroll
            for (int j = 0; j < 8; ++j) {
                bf16 xq = __float2bfloat16(br[j]);
                bv[j] = *(short*)&xq;
            }
            f32x4 acc0 = {}, acc1 = {};
            acc0 = __builtin_amdgcn_mfma_f32_16x16x32_bf16(a0, bv, acc0, 0, 0, 0);
            acc1 = __builtin_amdgcn_mfma_f32_16x16x32_bf16(a1, bv, acc1, 0, 0, 0);
            float bias = dtb[d0 + dl];
#pragma unroll
            for (int r = 0; r < 4; ++r) {
                int t0 = ((l >> 4) << 2) + r;
                ldt[t0][dl] = __float2bfloat16(softplus_fast(acc0[r] + bias));
                int t1 = 16 + t0;
                if (t1 < SEQL)
                    ldt[t1][dl] = __float2bfloat16(softplus_fast(acc1[r] + bias));
            }
        }
    }
    __syncthreads();

    float DdA = Dp[dc], DdB = Dp[dc + 1];
    bool fast = true;
#pragma unroll
    for (int s = 0; s < DSTATE; ++s) {
        float aA = __expf(A_log[(size_t)dc * DSTATE + s]);
        float aB = __expf(A_log[(size_t)(dc + 1) * DSTATE + s]);
        fast = fast && (__builtin_fabsf(aA - (float)(s + 1)) < 2e-3f)
                    && (__builtin_fabsf(aB - (float)(s + 1)) < 2e-3f);
    }

    if (fast) {
        f32x4 sA[4] = {}, sB[4] = {};
#pragma unroll
        for (int t = 0; t < SEQL; ++t) {
            unsigned du = *(const unsigned*)(&ldt[t][2 * tid]);
            float dtA = lo16(du), dtB = hi16(du);
            float xA = lo16(xu[t]), xB = hi16(xu[t]);
            float zA = lo16(zu[t]), zB = hi16(zu[t]);
            float dxA = dtA * xA, dxB = dtB * xB;
            float qA = exp2f(-dtA * LOG2E), qB = exp2f(-dtB * LOG2E);
            float qA2 = qA * qA, qA4 = qA2 * qA2;
            float qB2 = qB * qB, qB4 = qB2 * qB2;
            f32x4 PA; PA[0] = qA; PA[1] = qA2; PA[2] = qA2 * qA; PA[3] = qA4;
            f32x4 PB; PB[0] = qB; PB[1] = qB2; PB[2] = qB2 * qB; PB[3] = qB4;
            const f32x4* Bp = (const f32x4*)&lBC[t][0];
            const f32x4* Cp = (const f32x4*)&lBC[t][16];
            f32x4 dxA4; dxA4[0] = dxA; dxA4[1] = dxA; dxA4[2] = dxA; dxA4[3] = dxA;
            f32x4 dxB4; dxB4[0] = dxB; dxB4[1] = dxB; dxB4[2] = dxB; dxB4[3] = dxB;
            f32x4 accA = {}, accB = {};
#pragma unroll
            for (int i = 0; i < 4; ++i) {
                f32x4 Bv = Bp[i], Cv = Cp[i];
                sA[i] = sA[i] * PA + Bv * dxA4; accA += sA[i] * Cv;
                sB[i] = sB[i] * PB + Bv * dxB4; accB += sB[i] * Cv;
                if (i < 3) { PA = PA * qA4; PB = PB * qB4; }
            }
            float yA = accA[0] + accA[1] + accA[2] + accA[3];
            float yB = accB[0] + accB[1] + accB[2] + accB[3];
            float gA = zA * __builtin_amdgcn_rcpf(1.f + exp2f(-zA * LOG2E));
            float gB = zB * __builtin_amdgcn_rcpf(1.f + exp2f(-zB * LOG2E));
            bf16 oA = __float2bfloat16((yA + DdA * xA) * gA);
            bf16 oB = __float2bfloat16((yB + DdB * xB) * gB);
            unsigned ou = ((unsigned)*(unsigned short*)&oB << 16) | *(unsigned short*)&oA;
            *(unsigned*)(xg + (size_t)t * (2 * DINNER)) = ou;
        }
    } else {
        float AA[DSTATE], AB[DSTATE];
#pragma unroll
        for (int s = 0; s < DSTATE; ++s) {
            AA[s] = -__expf(A_log[(size_t)dc * DSTATE + s]) * LOG2E;
            AB[s] = -__expf(A_log[(size_t)(dc + 1) * DSTATE + s]) * LOG2E;
        }
        float sA[DSTATE] = {}, sB[DSTATE] = {};
#pragma unroll
        for (int t = 0; t < SEQL; ++t) {
            unsigned du = *(const unsigned*)(&ldt[t][2 * tid]);
            float dtA = lo16(du), dtB = hi16(du);
            float xA = lo16(xu[t]), xB = hi16(xu[t]);
            float zA = lo16(zu[t]), zB = hi16(zu[t]);
            float dxA = dtA * xA, dxB = dtB * xB;
            float yA = 0.f, yB = 0.f;
#pragma unroll
            for (int s = 0; s < DSTATE; ++s) {
                float Bv = lBC[t][s], Cv = lBC[t][16 + s];
                sA[s] = fmaf(sA[s], exp2f(dtA * AA[s]), dxA * Bv);
                sB[s] = fmaf(sB[s], exp2f(dtB * AB[s]), dxB * Bv);
                yA = fmaf(sA[s], Cv, yA);
                yB = fmaf(sB[s], Cv, yB);
            }
            float gA = zA * __builtin_amdgcn_rcpf(1.f + exp2f(-zA * LOG2E));
            float gB = zB * __builtin_amdgcn_rcpf(1.f + exp2f(-zB * LOG2E));
            bf16 oA = __float2bfloat16((yA + DdA * xA) * gA);
            bf16 oB = __float2bfloat16((yB + DdB * xB) * gB);
            unsigned ou = ((unsigned)*(unsigned short*)&oB << 16) | *(unsigned short*)&oA;
            *(unsigned*)(xg + (size_t)t * (2 * DINNER)) = ou;
        }
    }
}

// ---------------- final RMSNorm(last token) + classifier ----------------
__global__ __launch_bounds__(64) void head_kernel(const float* __restrict__ h,
                                                  const float* __restrict__ fw,
                                                  const float* __restrict__ clsw,
                                                  const float* __restrict__ clsb,
                                                  float* __restrict__ out) {
    int b = blockIdx.x;
    int lane = threadIdx.x;
    const float* row = h + ((size_t)b * SEQL + (SEQL - 1)) * DIMM;
    const float4* p = (const float4*)row;
    float4 v0 = p[lane * 2], v1 = p[lane * 2 + 1];
    float ss = v0.x * v0.x + v0.y * v0.y + v0.z * v0.z + v0.w * v0.w +
               v1.x * v1.x + v1.y * v1.y + v1.z * v1.z + v1.w * v1.w;
#pragma unroll
    for (int off = 32; off > 0; off >>= 1) ss += __shfl_down(ss, off);
    ss = __shfl(ss, 0);
    float inv = rsqrtf(ss * (1.f / DIMM) + EPSV);
    const float4* wp = (const float4*)fw;
    float4 w0 = wp[lane * 2], w1 = wp[lane * 2 + 1];
    float nv[8];
    nv[0] = v0.x * inv * w0.x; nv[1] = v0.y * inv * w0.y;
    nv[2] = v0.z * inv * w0.z; nv[3] = v0.w * inv * w0.w;
    nv[4] = v1.x * inv * w1.x; nv[5] = v1.y * inv * w1.y;
    nv[6] = v1.z * inv * w1.z; nv[7] = v1.w * inv * w1.w;
    for (int c = 0; c < 10; ++c) {
        const float* cr = clsw + (size_t)c * DIMM + lane * 8;
        float pacc = 0.f;
#pragma unroll
        for (int j = 0; j < 8; ++j) pacc = fmaf(nv[j], cr[j], pacc);
#pragma unroll
        for (int off = 32; off > 0; off >>= 1) pacc += __shfl_down(pacc, off);
        if (lane == 0) out[b * 10 + c] = pacc + clsb[c];
    }
}

extern "C" void kernel_launch(void* const* d_in, const int* in_sizes, int n_in,
                              void* d_out, int out_size, void* d_ws, size_t ws_size,
                              hipStream_t stream) {
    const float* x     = (const float*)d_in[0];
    const float* rpw   = (const float*)d_in[1];
    const float* rpb   = (const float*)d_in[2];
    const float* normw = (const float*)d_in[3];
    const float* inpw  = (const float*)d_in[4];
    const float* inpb  = (const float*)d_in[5];
    const float* convw = (const float*)d_in[6];
    const float* convb = (const float*)d_in[7];
    const float* xpw   = (const float*)d_in[8];
    const float* dtpw  = (const float*)d_in[9];
    const float* dtpb  = (const float*)d_in[10];
    const float* alog  = (const float*)d_in[11];
    const float* Dp    = (const float*)d_in[12];
    const float* outpw = (const float*)d_in[13];
    const float* outpb = (const float*)d_in[14];
    const float* fnw   = (const float*)d_in[15];
    const float* clsw  = (const float*)d_in[16];
    const float* clsb  = (const float*)d_in[17];
    float* out = (float*)d_out;

    // fixed region: bf16 copies of GEMM weights (converted once per launch)
    const int n_in_w  = 4 * 2 * DINNER * DIMM;   // 4,194,304
    const int n_out_w = 4 * DIMM * DINNER;       // 2,097,152
    const int n_xp_w  = 4 * XDBW * DINNER;       // 262,144
    char* base = (char*)d_ws;
    bf16* wbf_in  = (bf16*)base; base += (size_t)n_in_w * 2;
    bf16* wbf_out = (bf16*)base; base += (size_t)n_out_w * 2;
    bf16* wbf_xp  = (bf16*)base; base += (size_t)n_xp_w * 2;
    const size_t fixed = (size_t)(n_in_w + n_out_w + n_xp_w) * 2;

    // per-row bytes: h(f32,512) + nh(bf16,512) + xz(bf16,2048) + 2x xdb(f32,64)
    const size_t per_row = 512 * 4 + 512 * 2 + 2048 * 2 + 2 * 64 * 4;  // 7680 B
    const int cand[5] = {512, 256, 128, 64, 32};
    int Bc = 32;
    for (int i = 0; i < 5; ++i) {
        size_t R = (size_t)cand[i] * SEQL;
        if (fixed + R * per_row + 4096 <= ws_size) { Bc = cand[i]; break; }
    }
    const int chunks = BATCHN / Bc;
    const int R = Bc * SEQL;

    float* h   = (float*)base; base += (size_t)R * DIMM * 4;
    bf16* nh   = (bf16*)base;  base += (size_t)R * DIMM * 2;
    bf16* xz   = (bf16*)base;  base += (size_t)R * 2 * DINNER * 2;
    float* xdb = (float*)base; base += (size_t)R * XDBW * 4 * 2;  // two split-K halves

    wcvt_kernel<<<n_in_w / (256 * 8), 256, 0, stream>>>(inpw, wbf_in, n_in_w);
    wcvt_kernel<<<n_out_w / (256 * 8), 256, 0, stream>>>(outpw, wbf_out, n_out_w);
    wcvt_kernel<<<n_xp_w / (256 * 8), 256, 0, stream>>>(xpw, wbf_xp, n_xp_w);

    for (int c = 0; c < chunks; ++c) {
        const int b0 = c * Bc;
        rp_kernel<<<dim3(R, DIMM / 256), 256, 0, stream>>>(
            x + (size_t)b0 * 784, rpw, rpb, h);

        for (int l = 0; l < 4; ++l) {
            rmsn_kernel<<<R / 4, dim3(64, 4), 0, stream>>>(h, normw + (size_t)l * DIMM, nh);

            g_inproj<<<dim3(R / 128, (2 * DINNER) / 128), 256, 0, stream>>>(
                nh, wbf_in + (size_t)l * 2 * DINNER * DIMM, inpb + (size_t)l * 2 * DINNER, xz);

            conv_kernel<<<(Bc * DINNER / 2) / 256, 256, 0, stream>>>(
                xz, convw + (size_t)l * DINNER * 4, convb + (size_t)l * DINNER);

            g_xdbk<<<dim3(R / 64, 1, 2), 256, 0, stream>>>(
                xz, wbf_xp + (size_t)l * XDBW * DINNER, xdb, (size_t)R * XDBW);

            scan_kernel<<<Bc * 4, 128, 0, stream>>>(
                xz, xdb, xdb + (size_t)R * XDBW,
                dtpw + (size_t)l * DINNER * DTRANK, dtpb + (size_t)l * DINNER,
                alog + (size_t)l * DINNER * DSTATE, Dp + (size_t)l * DINNER);

            g_outproj<<<dim3(R / 128, DIMM / 128), 256, 0, stream>>>(
                xz, wbf_out + (size_t)l * DIMM * DINNER, outpb + (size_t)l * DIMM, h);
        }
        head_kernel<<<Bc, 64, 0, stream>>>(h, fnw, clsw, clsb, out + (size_t)b0 * 10);
    }
}

// Round 16
// 729.623 us; speedup vs baseline: 1.2327x; 1.2327x over previous
//
#include <hip/hip_runtime.h>
#include <hip/hip_bf16.h>

#define BATCHN 512
#define SEQL 28
#define DIMM 512
#define DINNER 1024
#define DSTATE 16
#define DTRANK 32
#define XDBW 64                 // DT_RANK + 2*D_STATE
#define EPSV 1e-6f
#define LDK 40                  // padded LDS stride for scan's lA only
#define LOG2E 1.442695041f
#define LN2F 0.6931471806f

typedef __hip_bfloat16 bf16;
using f32x4 = __attribute__((ext_vector_type(4))) float;
using bf16x8 = __attribute__((ext_vector_type(8))) short;

typedef __attribute__((address_space(1))) const void* gas1_t;
typedef __attribute__((address_space(3))) void* las3_t;

__device__ __forceinline__ float lo16(unsigned u) {
    unsigned short h = (unsigned short)u; bf16 v = *(bf16*)&h; return __bfloat162float(v);
}
__device__ __forceinline__ float hi16(unsigned u) {
    unsigned short h = (unsigned short)(u >> 16); bf16 v = *(bf16*)&h; return __bfloat162float(v);
}
__device__ __forceinline__ float softplus_fast(float v) {
    return (v > 20.f) ? v : LN2F * __log2f(1.f + exp2f(v * LOG2E));
}

// ---------------- weight f32 -> bf16 conversion (once per launch) ----------------
__global__ __launch_bounds__(256) void wcvt_kernel(const float* __restrict__ s,
                                                   bf16* __restrict__ d, int n) {
    int i = (blockIdx.x * 256 + threadIdx.x) * 8;
    if (i < n) {
        float4 a = *(const float4*)(s + i), b = *(const float4*)(s + i + 4);
        bf16 t[8];
        t[0] = __float2bfloat16(a.x); t[1] = __float2bfloat16(a.y);
        t[2] = __float2bfloat16(a.z); t[3] = __float2bfloat16(a.w);
        t[4] = __float2bfloat16(b.x); t[5] = __float2bfloat16(b.y);
        t[6] = __float2bfloat16(b.z); t[7] = __float2bfloat16(b.w);
        *(uint4*)(d + i) = *(uint4*)t;
    }
}

// ---------------- row projection: h[r,d] = W[d,:28] . x[r,:28] + b[d] ----------------
__global__ __launch_bounds__(256) void rp_kernel(const float* __restrict__ x,
                                                 const float* __restrict__ w,
                                                 const float* __restrict__ b,
                                                 float* __restrict__ h) {
    int row = blockIdx.x;
    int d = blockIdx.y * blockDim.x + threadIdx.x;
    __shared__ float xin[28];
    if (threadIdx.x < 28) xin[threadIdx.x] = x[row * 28 + threadIdx.x];
    __syncthreads();
    float acc = b[d];
#pragma unroll
    for (int k = 0; k < 28; ++k) acc = fmaf(w[d * 28 + k], xin[k], acc);
    h[(size_t)row * DIMM + d] = acc;
}

// ---------------- RMSNorm -> bf16 nh buffer (wave per row) ----------------
__global__ __launch_bounds__(256) void rmsn_kernel(const float* __restrict__ h,
                                                   const float* __restrict__ nw,
                                                   bf16* __restrict__ nh) {
    int row = blockIdx.x * blockDim.y + threadIdx.y;
    int lane = threadIdx.x;
    const float4* p = (const float4*)(h + (size_t)row * DIMM);
    float4 v0 = p[lane * 2], v1 = p[lane * 2 + 1];
    float ss = v0.x * v0.x + v0.y * v0.y + v0.z * v0.z + v0.w * v0.w +
               v1.x * v1.x + v1.y * v1.y + v1.z * v1.z + v1.w * v1.w;
#pragma unroll
    for (int off = 32; off > 0; off >>= 1) ss += __shfl_down(ss, off);
    ss = __shfl(ss, 0);
    float inv = rsqrtf(ss * (1.f / DIMM) + EPSV);
    const float4* wp = (const float4*)nw;
    float4 w0 = wp[lane * 2], w1 = wp[lane * 2 + 1];
    bf16 tmp[8];
    tmp[0] = __float2bfloat16(v0.x * inv * w0.x);
    tmp[1] = __float2bfloat16(v0.y * inv * w0.y);
    tmp[2] = __float2bfloat16(v0.z * inv * w0.z);
    tmp[3] = __float2bfloat16(v0.w * inv * w0.w);
    tmp[4] = __float2bfloat16(v1.x * inv * w1.x);
    tmp[5] = __float2bfloat16(v1.y * inv * w1.y);
    tmp[6] = __float2bfloat16(v1.z * inv * w1.z);
    tmp[7] = __float2bfloat16(v1.w * inv * w1.w);
    *(uint4*)(nh + (size_t)row * DIMM + lane * 8) = *(uint4*)tmp;
}

// ---------------- MFMA GEMM core (r13, unchanged): global_load_lds staging ----------------
template <typename TC, int BM, int BN, bool ADDC, bool HASBIAS, int SPLITK, bool COAL>
__device__ __forceinline__ void gemm_core(char* smem,
                                          const bf16* __restrict__ A, int lda,
                                          const bf16* __restrict__ W,
                                          const float* __restrict__ bias,
                                          TC* __restrict__ C, int ldc,
                                          int Kfull, size_t c_split, int bz) {
    constexpr int BK = 32;
    constexpr int MI = (BN == 128) ? 4 : 1;
    constexpr int NI = 4;
    bf16* As = (bf16*)smem;
    bf16* Bs = As + BM * BK;
    const int t = threadIdx.x;
    const int w = t >> 6, l = t & 63;
    const int bm = blockIdx.x * BM;
    const int bn = blockIdx.y * BN;
    const int wm = (BN == 128) ? (w >> 1) * 64 : w * 16;
    const int wn = (BN == 128) ? (w & 1) * 64 : 0;
    const int Kloop = Kfull / SPLITK;
    const int kb = (SPLITK > 1) ? bz * Kloop : 0;
    if (SPLITK > 1) C += (size_t)bz * c_split;

    f32x4 acc[MI][NI] = {};
    constexpr int CHA = BM / 64;
    constexpr int CHB = BN / 64;
    const int lrow = l >> 2;
    const int lcol = (l & 3) * 8;

    for (int k0 = 0; k0 < Kloop; k0 += BK) {
        const int kcur = kb + k0;
        __syncthreads();
#pragma unroll
        for (int i = 0; i < CHA; ++i) {
            int chunk = w * CHA + i;
            int row = chunk * 16 + lrow;
            __builtin_amdgcn_global_load_lds(
                (gas1_t)(const void*)(A + (size_t)(bm + row) * lda + kcur + lcol),
                (las3_t)(void*)(As + chunk * 512), 16, 0, 0);
        }
#pragma unroll
        for (int i = 0; i < CHB; ++i) {
            int chunk = w * CHB + i;
            int row = chunk * 16 + lrow;
            __builtin_amdgcn_global_load_lds(
                (gas1_t)(const void*)(W + (size_t)(bn + row) * Kfull + kcur + lcol),
                (las3_t)(void*)(Bs + chunk * 512), 16, 0, 0);
        }
        __syncthreads();
        bf16x8 af[MI], bfr[NI];
#pragma unroll
        for (int mi = 0; mi < MI; ++mi)
            af[mi] = *(const bf16x8*)(&As[(wm + mi * 16 + (l & 15)) * BK + (l >> 4) * 8]);
#pragma unroll
        for (int ni = 0; ni < NI; ++ni)
            bfr[ni] = *(const bf16x8*)(&Bs[(wn + ni * 16 + (l & 15)) * BK + (l >> 4) * 8]);
#pragma unroll
        for (int mi = 0; mi < MI; ++mi)
#pragma unroll
            for (int ni = 0; ni < NI; ++ni)
                acc[mi][ni] = __builtin_amdgcn_mfma_f32_16x16x32_bf16(af[mi], bfr[ni], acc[mi][ni], 0, 0, 0);
    }

    if constexpr (COAL && sizeof(TC) == 2) {
        __syncthreads();
        bf16* my = (bf16*)smem + w * (16 * 72);
        float bv[NI];
#pragma unroll
        for (int ni = 0; ni < NI; ++ni)
            bv[ni] = HASBIAS ? bias[bn + wn + ni * 16 + (l & 15)] : 0.f;
#pragma unroll
        for (int mi = 0; mi < MI; ++mi) {
#pragma unroll
            for (int ni = 0; ni < NI; ++ni)
#pragma unroll
                for (int r = 0; r < 4; ++r)
                    my[(((l >> 4) << 2) + r) * 72 + ni * 16 + (l & 15)] =
                        __float2bfloat16(acc[mi][ni][r] + bv[ni]);
            __syncthreads();
#pragma unroll
            for (int p = 0; p < 2; ++p) {
                int idx = p * 64 + l;
                int rr = idx >> 3, c8 = (idx & 7) * 8;
                uint4 vv = *(const uint4*)(&my[rr * 72 + c8]);
                *(uint4*)((bf16*)C + (size_t)(bm + wm + mi * 16 + rr) * ldc + bn + wn + c8) = vv;
            }
            __syncthreads();
        }
    } else if constexpr (COAL && sizeof(TC) == 4) {
        __syncthreads();
        float* myf = (float*)smem + w * (16 * 72);
        float bv[NI];
#pragma unroll
        for (int ni = 0; ni < NI; ++ni)
            bv[ni] = HASBIAS ? bias[bn + wn + ni * 16 + (l & 15)] : 0.f;
#pragma unroll
        for (int mi = 0; mi < MI; ++mi) {
#pragma unroll
            for (int ni = 0; ni < NI; ++ni)
#pragma unroll
                for (int r = 0; r < 4; ++r)
                    myf[(((l >> 4) << 2) + r) * 72 + ni * 16 + (l & 15)] = acc[mi][ni][r] + bv[ni];
            __syncthreads();
            int rr = l >> 2, c0 = l & 3;
            float* crow = (float*)C + (size_t)(bm + wm + mi * 16 + rr) * ldc + bn + wn;
#pragma unroll
            for (int c = 0; c < 4; ++c) {
                int slot = c0 + 4 * c;
                float4 v = *(float4*)(&myf[rr * 72 + slot * 4]);
                if (ADDC) {
                    float4 cc = *(const float4*)(crow + slot * 4);
                    v.x += cc.x; v.y += cc.y; v.z += cc.z; v.w += cc.w;
                }
                *(float4*)(crow + slot * 4) = v;
            }
            __syncthreads();
        }
    } else {
#pragma unroll
        for (int mi = 0; mi < MI; ++mi)
#pragma unroll
            for (int ni = 0; ni < NI; ++ni) {
                int col = bn + wn + ni * 16 + (l & 15);
                int rowb = bm + wm + mi * 16 + ((l >> 4) << 2);
                float bv = HASBIAS ? bias[col] : 0.f;
#pragma unroll
                for (int r = 0; r < 4; ++r) {
                    float v = acc[mi][ni][r] + bv;
                    size_t off = (size_t)(rowb + r) * ldc + col;
                    if (ADDC) v += ((float*)C)[off];
                    ((float*)C)[off] = v;
                }
            }
    }
}

__global__ __launch_bounds__(256) void g_inproj(const bf16* A, const bf16* W, const float* bias,
                                                bf16* C) {
    __shared__ char smem[16384];
    gemm_core<bf16, 128, 128, false, true, 1, true>(smem, A, DIMM, W, bias, C, 2 * DINNER, DIMM, 0, 0);
}
__global__ __launch_bounds__(256) void g_xdbk(const bf16* A, const bf16* W, float* C, size_t c_split) {
    __shared__ char smem[8192];
    gemm_core<float, 64, 64, false, false, 2, false>(smem, A, 2 * DINNER, W, nullptr, C, XDBW, DINNER,
                                                     c_split, blockIdx.z);
}
__global__ __launch_bounds__(256) void g_outproj(const bf16* A, const bf16* W, const float* bias,
                                                 float* C) {
    __shared__ char smem[18432];
    gemm_core<float, 128, 128, true, true, 1, true>(smem, A, 2 * DINNER, W, bias, C, DIMM, DINNER, 0, 0);
}

// ---------------- depthwise causal conv (k=4) + SiLU; in-place on x-half; 2 d/thread ----------------
__global__ __launch_bounds__(256) void conv_kernel(bf16* __restrict__ xz,
                                                   const float* __restrict__ cw,
                                                   const float* __restrict__ cb) {
    int gid = blockIdx.x * blockDim.x + threadIdx.x;
    int b = gid >> 9, dp = gid & 511;
    int d = dp * 2;
    float4 wA = *(const float4*)(cw + d * 4);
    float4 wB = *(const float4*)(cw + d * 4 + 4);
    float bA = cb[d], bB = cb[d + 1];
    bf16* col = xz + (size_t)b * SEQL * (2 * DINNER) + d;
    float a0 = 0.f, a1 = 0.f, a2 = 0.f, b0 = 0.f, b1 = 0.f, b2 = 0.f;
#pragma unroll
    for (int t = 0; t < SEQL; ++t) {
        unsigned u = *(const unsigned*)(col + (size_t)t * (2 * DINNER));
        float a3 = lo16(u), b3 = hi16(u);
        float va = fmaf(wA.x, a0, fmaf(wA.y, a1, fmaf(wA.z, a2, fmaf(wA.w, a3, bA))));
        float vb = fmaf(wB.x, b0, fmaf(wB.y, b1, fmaf(wB.z, b2, fmaf(wB.w, b3, bB))));
        float sa = va * __builtin_amdgcn_rcpf(1.f + exp2f(-va * LOG2E));
        float sb = vb * __builtin_amdgcn_rcpf(1.f + exp2f(-vb * LOG2E));
        bf16 ra = __float2bfloat16(sa), rb = __float2bfloat16(sb);
        unsigned ur = ((unsigned)*(unsigned short*)&rb << 16) | *(unsigned short*)&ra;
        *(unsigned*)(col + (size_t)t * (2 * DINNER)) = ur;
        a0 = a1; a1 = a2; a2 = a3;
        b0 = b1; b1 = b2; b2 = b3;
    }
}

// ---------------- fused scan v4: r14 structure + 4-deep x/z software pipeline ----------------
// r14 (93us): VALUBusy 36%, occ 29% -> per-t global x/z loads unhidden in serial loop.
// r15's full-28 prefetch blew VGPR to 160 / occ to 12% (too extreme). This: 4-deep
// ring of NAMED scalars (no arrays -> no scratch), loads for t+4 issued right after
// consuming t. +16 VGPR over r14's 64, under (128,2)'s 256 cap; LDS stays the
// occupancy limit (7 blocks/CU).
__global__ __launch_bounds__(128, 2) void scan_kernel(bf16* __restrict__ xz,
                                                      const float* __restrict__ xdb0,
                                                      const float* __restrict__ xdb1,
                                                      const float* __restrict__ dtw,
                                                      const float* __restrict__ dtb,
                                                      const float* __restrict__ A_log,
                                                      const float* __restrict__ Dp) {
    const int b = blockIdx.x >> 2;
    const int d0 = (blockIdx.x & 3) << 8;
    const int tid = threadIdx.x;            // 0..127
    const int w = tid >> 6, l = tid & 63;   // 2 waves

    __shared__ bf16 ldt[SEQL][264];
    __shared__ bf16 lA[32][LDK];
    __shared__ float lBC[SEQL][36];

    const float* xr0 = xdb0 + (size_t)b * SEQL * XDBW;
    const float* xr1 = xdb1 + (size_t)b * SEQL * XDBW;

    // ---- stage A = xdb_dt (28x32, summed halves, f32->bf16, rows 28-31 zero) ----
#pragma unroll
    for (int k = 0; k < 8; ++k) {
        int flat = k * 128 + tid;
        int t = flat >> 5, j = flat & 31;
        float v = (t < SEQL) ? xr0[t * XDBW + j] + xr1[t * XDBW + j] : 0.f;
        lA[t][j] = __float2bfloat16(v);
    }
    // ---- stage B/C (28x32, summed) ----
#pragma unroll
    for (int k = 0; k < 7; ++k) {
        int idx = k * 128 + tid;
        int t = idx >> 5, j = idx & 31;
        lBC[t][j] = xr0[t * XDBW + 32 + j] + xr1[t * XDBW + 32 + j];
    }
    __syncthreads();

    // ---- dt = softplus(xdb_dt @ dtw^T + dtb) via MFMA; wave w covers cols w*128..+127 ----
    {
        const int col = l & 15;
        const int ksl = (l >> 4) * 8;
        bf16x8 a0 = *(const bf16x8*)(&lA[col][ksl]);
        bf16x8 a1 = *(const bf16x8*)(&lA[16 + col][ksl]);
#pragma unroll
        for (int ni = 0; ni < 8; ++ni) {
            int dl = w * 128 + ni * 16 + col;
            const float* br = dtw + (size_t)(d0 + dl) * DTRANK + ksl;
            bf16x8 bv;
#pragma unroll
            for (int j = 0; j < 8; ++j) {
                bf16 xq = __float2bfloat16(br[j]);
                bv[j] = *(short*)&xq;
            }
            f32x4 acc0 = {}, acc1 = {};
            acc0 = __builtin_amdgcn_mfma_f32_16x16x32_bf16(a0, bv, acc0, 0, 0, 0);
            acc1 = __builtin_amdgcn_mfma_f32_16x16x32_bf16(a1, bv, acc1, 0, 0, 0);
            float bias = dtb[d0 + dl];
#pragma unroll
            for (int r = 0; r < 4; ++r) {
                int t0 = ((l >> 4) << 2) + r;
                ldt[t0][dl] = __float2bfloat16(softplus_fast(acc0[r] + bias));
                int t1 = 16 + t0;
                if (t1 < SEQL)
                    ldt[t1][dl] = __float2bfloat16(softplus_fast(acc1[r] + bias));
            }
        }
    }
    __syncthreads();

    const int dc = d0 + 2 * tid;            // channel pair
    float DdA = Dp[dc], DdB = Dp[dc + 1];
    bool fast = true;
#pragma unroll
    for (int s = 0; s < DSTATE; ++s) {
        float aA = __expf(A_log[(size_t)dc * DSTATE + s]);
        float aB = __expf(A_log[(size_t)(dc + 1) * DSTATE + s]);
        fast = fast && (__builtin_fabsf(aA - (float)(s + 1)) < 2e-3f)
                    && (__builtin_fabsf(aB - (float)(s + 1)) < 2e-3f);
    }

    bf16* xg = xz + (size_t)b * SEQL * (2 * DINNER) + dc;

    if (fast) {
        f32x4 sA[4] = {}, sB[4] = {};
        // 4-deep pipeline registers (named scalars; 28 = 7 groups of 4)
        unsigned xu0 = *(const unsigned*)(xg + 0 * (2 * DINNER));
        unsigned zu0 = *(const unsigned*)(xg + 0 * (2 * DINNER) + DINNER);
        unsigned xu1 = *(const unsigned*)(xg + 1 * (2 * DINNER));
        unsigned zu1 = *(const unsigned*)(xg + 1 * (2 * DINNER) + DINNER);
        unsigned xu2 = *(const unsigned*)(xg + 2 * (2 * DINNER));
        unsigned zu2 = *(const unsigned*)(xg + 2 * (2 * DINNER) + DINNER);
        unsigned xu3 = *(const unsigned*)(xg + 3 * (2 * DINNER));
        unsigned zu3 = *(const unsigned*)(xg + 3 * (2 * DINNER) + DINNER);

        auto body = [&](int t, unsigned xuv, unsigned zuv) {
            unsigned du = *(const unsigned*)(&ldt[t][2 * tid]);
            float dtA = lo16(du), dtB = hi16(du);
            float xA = lo16(xuv), xB = hi16(xuv);
            float zA = lo16(zuv), zB = hi16(zuv);
            float dxA = dtA * xA, dxB = dtB * xB;
            float qA = exp2f(-dtA * LOG2E), qB = exp2f(-dtB * LOG2E);
            float qA2 = qA * qA, qA4 = qA2 * qA2;
            float qB2 = qB * qB, qB4 = qB2 * qB2;
            f32x4 PA; PA[0] = qA; PA[1] = qA2; PA[2] = qA2 * qA; PA[3] = qA4;
            f32x4 PB; PB[0] = qB; PB[1] = qB2; PB[2] = qB2 * qB; PB[3] = qB4;
            const f32x4* Bp = (const f32x4*)&lBC[t][0];
            const f32x4* Cp = (const f32x4*)&lBC[t][16];
            f32x4 dxA4; dxA4[0] = dxA; dxA4[1] = dxA; dxA4[2] = dxA; dxA4[3] = dxA;
            f32x4 dxB4; dxB4[0] = dxB; dxB4[1] = dxB; dxB4[2] = dxB; dxB4[3] = dxB;
            f32x4 accA = {}, accB = {};
#pragma unroll
            for (int i = 0; i < 4; ++i) {
                f32x4 Bv = Bp[i], Cv = Cp[i];
                sA[i] = sA[i] * PA + Bv * dxA4; accA += sA[i] * Cv;
                sB[i] = sB[i] * PB + Bv * dxB4; accB += sB[i] * Cv;
                if (i < 3) { PA = PA * qA4; PB = PB * qB4; }
            }
            float yA = accA[0] + accA[1] + accA[2] + accA[3];
            float yB = accB[0] + accB[1] + accB[2] + accB[3];
            float gA = zA * __builtin_amdgcn_rcpf(1.f + exp2f(-zA * LOG2E));
            float gB = zB * __builtin_amdgcn_rcpf(1.f + exp2f(-zB * LOG2E));
            bf16 oA = __float2bfloat16((yA + DdA * xA) * gA);
            bf16 oB = __float2bfloat16((yB + DdB * xB) * gB);
            unsigned ou = ((unsigned)*(unsigned short*)&oB << 16) | *(unsigned short*)&oA;
            *(unsigned*)(xg + (size_t)t * (2 * DINNER)) = ou;
        };

#pragma unroll
        for (int tb = 0; tb < SEQL; tb += 4) {
            body(tb + 0, xu0, zu0);
            if (tb + 4 < SEQL) {
                xu0 = *(const unsigned*)(xg + (size_t)(tb + 4) * (2 * DINNER));
                zu0 = *(const unsigned*)(xg + (size_t)(tb + 4) * (2 * DINNER) + DINNER);
            }
            body(tb + 1, xu1, zu1);
            if (tb + 5 < SEQL) {
                xu1 = *(const unsigned*)(xg + (size_t)(tb + 5) * (2 * DINNER));
                zu1 = *(const unsigned*)(xg + (size_t)(tb + 5) * (2 * DINNER) + DINNER);
            }
            body(tb + 2, xu2, zu2);
            if (tb + 6 < SEQL) {
                xu2 = *(const unsigned*)(xg + (size_t)(tb + 6) * (2 * DINNER));
                zu2 = *(const unsigned*)(xg + (size_t)(tb + 6) * (2 * DINNER) + DINNER);
            }
            body(tb + 3, xu3, zu3);
            if (tb + 7 < SEQL) {
                xu3 = *(const unsigned*)(xg + (size_t)(tb + 7) * (2 * DINNER));
                zu3 = *(const unsigned*)(xg + (size_t)(tb + 7) * (2 * DINNER) + DINNER);
            }
        }
    } else {
        float AA[DSTATE], AB[DSTATE];
#pragma unroll
        for (int s = 0; s < DSTATE; ++s) {
            AA[s] = -__expf(A_log[(size_t)dc * DSTATE + s]) * LOG2E;
            AB[s] = -__expf(A_log[(size_t)(dc + 1) * DSTATE + s]) * LOG2E;
        }
        float sA[DSTATE] = {}, sB[DSTATE] = {};
        for (int t = 0; t < SEQL; ++t) {
            unsigned xuv = *(const unsigned*)(xg + (size_t)t * (2 * DINNER));
            unsigned zuv = *(const unsigned*)(xg + (size_t)t * (2 * DINNER) + DINNER);
            unsigned du = *(const unsigned*)(&ldt[t][2 * tid]);
            float dtA = lo16(du), dtB = hi16(du);
            float xA = lo16(xuv), xB = hi16(xuv);
            float zA = lo16(zuv), zB = hi16(zuv);
            float dxA = dtA * xA, dxB = dtB * xB;
            float yA = 0.f, yB = 0.f;
#pragma unroll
            for (int s = 0; s < DSTATE; ++s) {
                float Bv = lBC[t][s], Cv = lBC[t][16 + s];
                sA[s] = fmaf(sA[s], exp2f(dtA * AA[s]), dxA * Bv);
                sB[s] = fmaf(sB[s], exp2f(dtB * AB[s]), dxB * Bv);
                yA = fmaf(sA[s], Cv, yA);
                yB = fmaf(sB[s], Cv, yB);
            }
            float gA = zA * __builtin_amdgcn_rcpf(1.f + exp2f(-zA * LOG2E));
            float gB = zB * __builtin_amdgcn_rcpf(1.f + exp2f(-zB * LOG2E));
            bf16 oA = __float2bfloat16((yA + DdA * xA) * gA);
            bf16 oB = __float2bfloat16((yB + DdB * xB) * gB);
            unsigned ou = ((unsigned)*(unsigned short*)&oB << 16) | *(unsigned short*)&oA;
            *(unsigned*)(xg + (size_t)t * (2 * DINNER)) = ou;
        }
    }
}

// ---------------- final RMSNorm(last token) + classifier ----------------
__global__ __launch_bounds__(64) void head_kernel(const float* __restrict__ h,
                                                  const float* __restrict__ fw,
                                                  const float* __restrict__ clsw,
                                                  const float* __restrict__ clsb,
                                                  float* __restrict__ out) {
    int b = blockIdx.x;
    int lane = threadIdx.x;
    const float* row = h + ((size_t)b * SEQL + (SEQL - 1)) * DIMM;
    const float4* p = (const float4*)row;
    float4 v0 = p[lane * 2], v1 = p[lane * 2 + 1];
    float ss = v0.x * v0.x + v0.y * v0.y + v0.z * v0.z + v0.w * v0.w +
               v1.x * v1.x + v1.y * v1.y + v1.z * v1.z + v1.w * v1.w;
#pragma unroll
    for (int off = 32; off > 0; off >>= 1) ss += __shfl_down(ss, off);
    ss = __shfl(ss, 0);
    float inv = rsqrtf(ss * (1.f / DIMM) + EPSV);
    const float4* wp = (const float4*)fw;
    float4 w0 = wp[lane * 2], w1 = wp[lane * 2 + 1];
    float nv[8];
    nv[0] = v0.x * inv * w0.x; nv[1] = v0.y * inv * w0.y;
    nv[2] = v0.z * inv * w0.z; nv[3] = v0.w * inv * w0.w;
    nv[4] = v1.x * inv * w1.x; nv[5] = v1.y * inv * w1.y;
    nv[6] = v1.z * inv * w1.z; nv[7] = v1.w * inv * w1.w;
    for (int c = 0; c < 10; ++c) {
        const float* cr = clsw + (size_t)c * DIMM + lane * 8;
        float pacc = 0.f;
#pragma unroll
        for (int j = 0; j < 8; ++j) pacc = fmaf(nv[j], cr[j], pacc);
#pragma unroll
        for (int off = 32; off > 0; off >>= 1) pacc += __shfl_down(pacc, off);
        if (lane == 0) out[b * 10 + c] = pacc + clsb[c];
    }
}

extern "C" void kernel_launch(void* const* d_in, const int* in_sizes, int n_in,
                              void* d_out, int out_size, void* d_ws, size_t ws_size,
                              hipStream_t stream) {
    const float* x     = (const float*)d_in[0];
    const float* rpw   = (const float*)d_in[1];
    const float* rpb   = (const float*)d_in[2];
    const float* normw = (const float*)d_in[3];
    const float* inpw  = (const float*)d_in[4];
    const float* inpb  = (const float*)d_in[5];
    const float* convw = (const float*)d_in[6];
    const float* convb = (const float*)d_in[7];
    const float* xpw   = (const float*)d_in[8];
    const float* dtpw  = (const float*)d_in[9];
    const float* dtpb  = (const float*)d_in[10];
    const float* alog  = (const float*)d_in[11];
    const float* Dp    = (const float*)d_in[12];
    const float* outpw = (const float*)d_in[13];
    const float* outpb = (const float*)d_in[14];
    const float* fnw   = (const float*)d_in[15];
    const float* clsw  = (const float*)d_in[16];
    const float* clsb  = (const float*)d_in[17];
    float* out = (float*)d_out;

    // fixed region: bf16 copies of GEMM weights (converted once per launch)
    const int n_in_w  = 4 * 2 * DINNER * DIMM;   // 4,194,304
    const int n_out_w = 4 * DIMM * DINNER;       // 2,097,152
    const int n_xp_w  = 4 * XDBW * DINNER;       // 262,144
    char* base = (char*)d_ws;
    bf16* wbf_in  = (bf16*)base; base += (size_t)n_in_w * 2;
    bf16* wbf_out = (bf16*)base; base += (size_t)n_out_w * 2;
    bf16* wbf_xp  = (bf16*)base; base += (size_t)n_xp_w * 2;
    const size_t fixed = (size_t)(n_in_w + n_out_w + n_xp_w) * 2;

    // per-row bytes: h(f32,512) + nh(bf16,512) + xz(bf16,2048) + 2x xdb(f32,64)
    const size_t per_row = 512 * 4 + 512 * 2 + 2048 * 2 + 2 * 64 * 4;  // 7680 B
    const int cand[5] = {512, 256, 128, 64, 32};
    int Bc = 32;
    for (int i = 0; i < 5; ++i) {
        size_t R = (size_t)cand[i] * SEQL;
        if (fixed + R * per_row + 4096 <= ws_size) { Bc = cand[i]; break; }
    }
    const int chunks = BATCHN / Bc;
    const int R = Bc * SEQL;

    float* h   = (float*)base; base += (size_t)R * DIMM * 4;
    bf16* nh   = (bf16*)base;  base += (size_t)R * DIMM * 2;
    bf16* xz   = (bf16*)base;  base += (size_t)R * 2 * DINNER * 2;
    float* xdb = (float*)base; base += (size_t)R * XDBW * 4 * 2;  // two split-K halves

    wcvt_kernel<<<n_in_w / (256 * 8), 256, 0, stream>>>(inpw, wbf_in, n_in_w);
    wcvt_kernel<<<n_out_w / (256 * 8), 256, 0, stream>>>(outpw, wbf_out, n_out_w);
    wcvt_kernel<<<n_xp_w / (256 * 8), 256, 0, stream>>>(xpw, wbf_xp, n_xp_w);

    for (int c = 0; c < chunks; ++c) {
        const int b0 = c * Bc;
        rp_kernel<<<dim3(R, DIMM / 256), 256, 0, stream>>>(
            x + (size_t)b0 * 784, rpw, rpb, h);

        for (int l = 0; l < 4; ++l) {
            rmsn_kernel<<<R / 4, dim3(64, 4), 0, stream>>>(h, normw + (size_t)l * DIMM, nh);

            g_inproj<<<dim3(R / 128, (2 * DINNER) / 128), 256, 0, stream>>>(
                nh, wbf_in + (size_t)l * 2 * DINNER * DIMM, inpb + (size_t)l * 2 * DINNER, xz);

            conv_kernel<<<(Bc * DINNER / 2) / 256, 256, 0, stream>>>(
                xz, convw + (size_t)l * DINNER * 4, convb + (size_t)l * DINNER);

            g_xdbk<<<dim3(R / 64, 1, 2), 256, 0, stream>>>(
                xz, wbf_xp + (size_t)l * XDBW * DINNER, xdb, (size_t)R * XDBW);

            scan_kernel<<<Bc * 4, 128, 0, stream>>>(
                xz, xdb, xdb + (size_t)R * XDBW,
                dtpw + (size_t)l * DINNER * DTRANK, dtpb + (size_t)l * DINNER,
                alog + (size_t)l * DINNER * DSTATE, Dp + (size_t)l * DINNER);

            g_outproj<<<dim3(R / 128, DIMM / 128), 256, 0, stream>>>(
                xz, wbf_out + (size_t)l * DIMM * DINNER, outpb + (size_t)l * DIMM, h);
        }
        head_kernel<<<Bc, 64, 0, stream>>>(h, fnw, clsw, clsb, out + (size_t)b0 * 10);
    }
}